// Round 9
// baseline (571.309 us; speedup 1.0000x reference)
//
#include <hip/hip_runtime.h>
#include <hip/hip_bf16.h>
#include <cstring>

// GraphSAGE 2-layer. mean_agg(h)@W == mean_agg(h@W): project, then aggregate.
// No CSR: edges are bucket-sorted by dst>>8 (fixed-capacity buckets), and the
// aggregation kernels read epart directly, accumulating into per-bucket LDS
// fp32 accumulators (256 nodes x cols, ds_add_f32). Degree counted in LDS too.
// selfo/t1/h1/t2 all bf16 (fp32 accumulation everywhere).

#define FEATS 64
#define CLS   16
#define EPT   16      // edges/thread in partition kernel (4096 edges/block)
#define CAP   5120    // bucket capacity; mean 4081 edges/bucket, 16 sigma margin

typedef unsigned short bf16_t;

__device__ __forceinline__ float bfbits2f(unsigned lo16) {
    unsigned v = lo16 << 16;
    float f;
    __builtin_memcpy(&f, &v, 4);
    return f;
}
__device__ __forceinline__ bf16_t f2bf(float f) {
    unsigned u;
    __builtin_memcpy(&u, &f, 4);
    u = (u + 0x7FFFu + ((u >> 16) & 1u)) >> 16;   // round-to-nearest-even
    return (bf16_t)u;
}
__device__ __forceinline__ unsigned pack2(float a, float b) {
    return (unsigned)f2bf(a) | ((unsigned)f2bf(b) << 16);
}
__device__ __forceinline__ void acc8(float* ap, uint4 r) {
    atomicAdd(ap + 0, bfbits2f(r.x & 0xffff));
    atomicAdd(ap + 1, bfbits2f(r.x >> 16));
    atomicAdd(ap + 2, bfbits2f(r.y & 0xffff));
    atomicAdd(ap + 3, bfbits2f(r.y >> 16));
    atomicAdd(ap + 4, bfbits2f(r.z & 0xffff));
    atomicAdd(ap + 5, bfbits2f(r.z >> 16));
    atomicAdd(ap + 6, bfbits2f(r.w & 0xffff));
    atomicAdd(ap + 7, bfbits2f(r.w >> 16));
}

// ---------------- partition: scatter packed (src<<8)|(dst&255) into fixed-cap buckets ----------------
__global__ __launch_bounds__(256) void partition_kernel(const int* __restrict__ src,
                                                        const int* __restrict__ dst,
                                                        int* __restrict__ bucket_cnt,
                                                        int* __restrict__ epart, int E) {
    __shared__ int hist[256];
    __shared__ int base[256];
    int t = threadIdx.x;
    int e0 = blockIdx.x * (256 * EPT);
    hist[t] = 0;
    __syncthreads();
    int pk[EPT];
    int bk[EPT];
#pragma unroll
    for (int j = 0; j < EPT; ++j) {
        int e = e0 + j * 256 + t;
        if (e < E) {
            int d = dst[e];
            pk[j] = (src[e] << 8) | (d & 255);
            bk[j] = d >> 8;
            atomicAdd(&hist[bk[j]], 1);
        } else bk[j] = -1;
    }
    __syncthreads();
    int c = hist[t];
    if (c) base[t] = atomicAdd(&bucket_cnt[t], c);
    hist[t] = 0;
    __syncthreads();
#pragma unroll
    for (int j = 0; j < EPT; ++j) {
        if (bk[j] >= 0) {
            int r = atomicAdd(&hist[bk[j]], 1);
            epart[bk[j] * CAP + base[bk[j]] + r] = pk[j];
        }
    }
}

// ---------------- GEMM1: [N,64] x [64,128] -> selfo [N,64] bf16, t1 [N,64] bf16 ----------------
// 128-node tile. Thread t: m=t&31, g=t>>5 -> nodes {m,m+32,m+64,m+96}, cols [g*16,g*16+16).
__global__ __launch_bounds__(256) void gemm1_kernel(
    const float* __restrict__ x, const float* __restrict__ Ws,
    const float* __restrict__ Wn, bf16_t* __restrict__ selfo,
    bf16_t* __restrict__ t1, int N)
{
    __shared__ float Wc[64 * 128];   // 32 KB
    __shared__ float xs[128 * 65];   // 33.3 KB
    int t = threadIdx.x;
    int node0 = blockIdx.x * 128;

    for (int idx = t; idx < 64 * 128; idx += 256) {
        int k = idx >> 7, c = idx & 127;
        Wc[idx] = (c < 64) ? Ws[k * 64 + c] : Wn[k * 64 + (c - 64)];
    }
    for (int idx = t; idx < 128 * 16; idx += 256) {
        int row = idx >> 4, c4 = idx & 15;
        int node = node0 + row;
        float4 v = (node < N) ? ((const float4*)(x + (size_t)node * 64))[c4]
                              : make_float4(0.f, 0.f, 0.f, 0.f);
        float* p = &xs[row * 65 + c4 * 4];
        p[0] = v.x; p[1] = v.y; p[2] = v.z; p[3] = v.w;
    }
    __syncthreads();

    int m = t & 31;
    int g = t >> 5;            // 8 col-groups of 16
    float acc[4][16];
#pragma unroll
    for (int j = 0; j < 4; ++j)
#pragma unroll
        for (int c = 0; c < 16; ++c) acc[j][c] = 0.f;

    for (int k = 0; k < 64; ++k) {
        float w[16];
        const float* wp = &Wc[k * 128 + g * 16];
#pragma unroll
        for (int c = 0; c < 16; ++c) w[c] = wp[c];
        float a0 = xs[m * 65 + k];
        float a1 = xs[(m + 32) * 65 + k];
        float a2 = xs[(m + 64) * 65 + k];
        float a3 = xs[(m + 96) * 65 + k];
#pragma unroll
        for (int c = 0; c < 16; ++c) {
            acc[0][c] += a0 * w[c];
            acc[1][c] += a1 * w[c];
            acc[2][c] += a2 * w[c];
            acc[3][c] += a3 * w[c];
        }
    }
#pragma unroll
    for (int j = 0; j < 4; ++j) {
        int node = node0 + m + 32 * j;
        if (node < N) {
            bf16_t* dstp = ((g < 4) ? selfo : t1) + (size_t)node * 64 + (g & 3) * 16;
            uint4 p0, p1;
            p0.x = pack2(acc[j][0],  acc[j][1]);  p0.y = pack2(acc[j][2],  acc[j][3]);
            p0.z = pack2(acc[j][4],  acc[j][5]);  p0.w = pack2(acc[j][6],  acc[j][7]);
            p1.x = pack2(acc[j][8],  acc[j][9]);  p1.y = pack2(acc[j][10], acc[j][11]);
            p1.z = pack2(acc[j][12], acc[j][13]); p1.w = pack2(acc[j][14], acc[j][15]);
            *(uint4*)(dstp) = p0;
            *(uint4*)(dstp + 8) = p1;
        }
    }
}

// ---------------- agg64: per-bucket LDS aggregation of t1, fused layer-1 epilogue ----------------
// block b handles bucket b (nodes b*256..b*256+255, edges epart[b*CAP..+cnt)).
// 8 lanes/edge (uint4 = 8 bf16 each); LDS acc stride 65 (col 64 = degree).
__global__ __launch_bounds__(512) void agg64_kernel(
    const int* __restrict__ epart, const int* __restrict__ bucket_cnt,
    const bf16_t* __restrict__ t1, const bf16_t* __restrict__ selfo,
    const float* __restrict__ b1, bf16_t* __restrict__ h1, int N)
{
    __shared__ float acc[256 * 65];   // 66.6 KB
    int t = threadIdx.x;
    int b = blockIdx.x;
    for (int idx = t; idx < 256 * 65; idx += 512) acc[idx] = 0.f;
    __syncthreads();

    int ecnt = bucket_cnt[b];
    int ebeg = b * CAP;
    int sub = t >> 3;        // 64 edges in flight per iteration
    int q = t & 7;           // cols [q*8, q*8+8)
    int e = sub;
    for (; e + 64 < ecnt; e += 128) {   // 2-deep unroll: 2 rows in flight / thread
        int pk0 = epart[ebeg + e];
        int pk1 = epart[ebeg + e + 64];
        uint4 r0 = *(const uint4*)(t1 + (size_t)(pk0 >> 8) * 64 + q * 8);
        uint4 r1 = *(const uint4*)(t1 + (size_t)(pk1 >> 8) * 64 + q * 8);
        int ln0 = pk0 & 255, ln1 = pk1 & 255;
        acc8(&acc[ln0 * 65 + q * 8], r0);
        acc8(&acc[ln1 * 65 + q * 8], r1);
        if (q == 0) {
            atomicAdd(&acc[ln0 * 65 + 64], 1.0f);
            atomicAdd(&acc[ln1 * 65 + 64], 1.0f);
        }
    }
    for (; e < ecnt; e += 64) {
        int pk0 = epart[ebeg + e];
        uint4 r0 = *(const uint4*)(t1 + (size_t)(pk0 >> 8) * 64 + q * 8);
        int ln0 = pk0 & 255;
        acc8(&acc[ln0 * 65 + q * 8], r0);
        if (q == 0) atomicAdd(&acc[ln0 * 65 + 64], 1.0f);
    }
    __syncthreads();

    // epilogue: h1 = relu(selfo + acc/deg + b1), bf16
    for (int idx = t; idx < 256 * 16; idx += 512) {
        int ln = idx >> 4, c4 = idx & 15;
        int node = b * 256 + ln;
        if (node < N) {
            float inv = 1.f / fmaxf(acc[ln * 65 + 64], 1.f);
            uint2 su = *(const uint2*)(selfo + (size_t)node * 64 + c4 * 4);
            float4 bb = *(const float4*)(b1 + c4 * 4);
            const float* ap = &acc[ln * 65 + c4 * 4];
            float rx = fmaxf(bfbits2f(su.x & 0xffff) + ap[0] * inv + bb.x, 0.f);
            float ry = fmaxf(bfbits2f(su.x >> 16)    + ap[1] * inv + bb.y, 0.f);
            float rz = fmaxf(bfbits2f(su.y & 0xffff) + ap[2] * inv + bb.z, 0.f);
            float rw = fmaxf(bfbits2f(su.y >> 16)    + ap[3] * inv + bb.w, 0.f);
            uint2 pk2;
            pk2.x = pack2(rx, ry);
            pk2.y = pack2(rz, rw);
            *(uint2*)(h1 + (size_t)node * 64 + c4 * 4) = pk2;
        }
    }
}

// ---------------- GEMM2: h1(bf16) [N,64] x [64,32] -> out(self) [N,16] f32, t2 [N,16] bf16 ----------------
__global__ __launch_bounds__(256) void gemm2_kernel(
    const bf16_t* __restrict__ h1, const float* __restrict__ Ws,
    const float* __restrict__ Wn, float* __restrict__ outp,
    bf16_t* __restrict__ t2, int N)
{
    __shared__ float Wc[64 * 32];    // 8 KB
    __shared__ float xs[128 * 65];   // 33.3 KB
    int t = threadIdx.x;
    int node0 = blockIdx.x * 128;

    for (int idx = t; idx < 64 * 32; idx += 256) {
        int k = idx >> 5, c = idx & 31;
        Wc[idx] = (c < 16) ? Ws[k * 16 + c] : Wn[k * 16 + (c - 16)];
    }
    for (int idx = t; idx < 128 * 8; idx += 256) {
        int row = idx >> 3, c8 = idx & 7;
        int node = node0 + row;
        float* p = &xs[row * 65 + c8 * 8];
        if (node < N) {
            uint4 u = *(const uint4*)(h1 + (size_t)node * 64 + c8 * 8);
            p[0] = bfbits2f(u.x & 0xffff); p[1] = bfbits2f(u.x >> 16);
            p[2] = bfbits2f(u.y & 0xffff); p[3] = bfbits2f(u.y >> 16);
            p[4] = bfbits2f(u.z & 0xffff); p[5] = bfbits2f(u.z >> 16);
            p[6] = bfbits2f(u.w & 0xffff); p[7] = bfbits2f(u.w >> 16);
        } else {
            for (int qq = 0; qq < 8; ++qq) p[qq] = 0.f;
        }
    }
    __syncthreads();

    int m = t & 31;
    int g = t >> 5;            // 8 col-groups of 4
    float acc[4][4];
#pragma unroll
    for (int j = 0; j < 4; ++j)
#pragma unroll
        for (int c = 0; c < 4; ++c) acc[j][c] = 0.f;

    for (int k = 0; k < 64; ++k) {
        float w[4];
        const float* wp = &Wc[k * 32 + g * 4];
#pragma unroll
        for (int c = 0; c < 4; ++c) w[c] = wp[c];
        float a0 = xs[m * 65 + k];
        float a1 = xs[(m + 32) * 65 + k];
        float a2 = xs[(m + 64) * 65 + k];
        float a3 = xs[(m + 96) * 65 + k];
#pragma unroll
        for (int c = 0; c < 4; ++c) {
            acc[0][c] += a0 * w[c];
            acc[1][c] += a1 * w[c];
            acc[2][c] += a2 * w[c];
            acc[3][c] += a3 * w[c];
        }
    }
#pragma unroll
    for (int j = 0; j < 4; ++j) {
        int node = node0 + m + 32 * j;
        if (node < N) {
            if (g < 4) {
                *(float4*)(outp + (size_t)node * 16 + g * 4) =
                    make_float4(acc[j][0], acc[j][1], acc[j][2], acc[j][3]);
            } else {
                uint2 pk;
                pk.x = pack2(acc[j][0], acc[j][1]);
                pk.y = pack2(acc[j][2], acc[j][3]);
                *(uint2*)(t2 + (size_t)node * 16 + (g - 4) * 4) = pk;
            }
        }
    }
}

// ---------------- agg16: per-bucket LDS aggregation of t2, fused final epilogue ----------------
// 2 lanes/edge (uint4 = 8 bf16 each); LDS acc stride 17 (col 16 = degree).
__global__ __launch_bounds__(512) void agg16_kernel(
    const int* __restrict__ epart, const int* __restrict__ bucket_cnt,
    const bf16_t* __restrict__ t2, const float* __restrict__ b2,
    float* __restrict__ outp, int N)
{
    __shared__ float acc[256 * 17];   // 17.4 KB
    int t = threadIdx.x;
    int b = blockIdx.x;
    for (int idx = t; idx < 256 * 17; idx += 512) acc[idx] = 0.f;
    __syncthreads();

    int ecnt = bucket_cnt[b];
    int ebeg = b * CAP;
    int sub = t >> 1;        // 256 edges in flight per iteration
    int q = t & 1;           // cols [q*8, q*8+8)
    int e = sub;
    for (; e + 256 < ecnt; e += 512) {
        int pk0 = epart[ebeg + e];
        int pk1 = epart[ebeg + e + 256];
        uint4 r0 = *(const uint4*)(t2 + (size_t)(pk0 >> 8) * 16 + q * 8);
        uint4 r1 = *(const uint4*)(t2 + (size_t)(pk1 >> 8) * 16 + q * 8);
        int ln0 = pk0 & 255, ln1 = pk1 & 255;
        acc8(&acc[ln0 * 17 + q * 8], r0);
        acc8(&acc[ln1 * 17 + q * 8], r1);
        if (q == 0) {
            atomicAdd(&acc[ln0 * 17 + 16], 1.0f);
            atomicAdd(&acc[ln1 * 17 + 16], 1.0f);
        }
    }
    for (; e < ecnt; e += 256) {
        int pk0 = epart[ebeg + e];
        uint4 r0 = *(const uint4*)(t2 + (size_t)(pk0 >> 8) * 16 + q * 8);
        int ln0 = pk0 & 255;
        acc8(&acc[ln0 * 17 + q * 8], r0);
        if (q == 0) atomicAdd(&acc[ln0 * 17 + 16], 1.0f);
    }
    __syncthreads();

    // epilogue: out += acc/deg + b2
    for (int idx = t; idx < 256 * 4; idx += 512) {
        int ln = idx >> 2, c4 = idx & 3;
        int node = b * 256 + ln;
        if (node < N) {
            float inv = 1.f / fmaxf(acc[ln * 17 + 16], 1.f);
            const float* ap = &acc[ln * 17 + c4 * 4];
            float4 bb = *(const float4*)(b2 + c4 * 4);
            float4 o = *(const float4*)(outp + (size_t)node * 16 + c4 * 4);
            o.x += ap[0] * inv + bb.x;
            o.y += ap[1] * inv + bb.y;
            o.z += ap[2] * inv + bb.z;
            o.w += ap[3] * inv + bb.w;
            *(float4*)(outp + (size_t)node * 16 + c4 * 4) = o;
        }
    }
}

extern "C" void kernel_launch(void* const* d_in, const int* in_sizes, int n_in,
                              void* d_out, int out_size, void* d_ws, size_t ws_size,
                              hipStream_t stream) {
    const float* x   = (const float*)d_in[0];
    const int*   src = (const int*)d_in[1];
    const int*   dst = (const int*)d_in[2];
    const float* Ws1 = (const float*)d_in[3];
    const float* Wn1 = (const float*)d_in[4];
    const float* b1  = (const float*)d_in[5];
    const float* Ws2 = (const float*)d_in[6];
    const float* Wn2 = (const float*)d_in[7];
    const float* b2  = (const float*)d_in[8];
    float* outp = (float*)d_out;

    const int N = in_sizes[0] / FEATS;   // 50000
    const int E = in_sizes[1];           // 800000
    const int B = (N + 255) / 256;       // buckets (196) — must be <= 256

    // workspace: bucket_cnt[256] | epart[B*CAP] | selfo bf16[N*64] | t1 bf16[N*64] |
    // h1 bf16[N*64] | t2 bf16[N*16]
    char* p = (char*)d_ws;
    auto align16 = [](char* q) { return (char*)(((size_t)q + 15) & ~(size_t)15); };
    int* bucket_cnt = (int*)p;             p = (char*)(bucket_cnt + 256);
    int* epart      = (int*)p;             p = (char*)(epart + (size_t)B * CAP);
    bf16_t* selfo   = (bf16_t*)align16(p); p = (char*)(selfo + (size_t)N * 64);
    bf16_t* t1      = (bf16_t*)align16(p); p = (char*)(t1 + (size_t)N * 64);
    bf16_t* h1      = (bf16_t*)align16(p); p = (char*)(h1 + (size_t)N * 64);
    bf16_t* t2      = (bf16_t*)align16(p);

    hipMemsetAsync(bucket_cnt, 0, 256 * sizeof(int), stream);

    partition_kernel<<<(E + 256 * EPT - 1) / (256 * EPT), 256, 0, stream>>>(
        src, dst, bucket_cnt, epart, E);
    gemm1_kernel<<<(N + 127) / 128, 256, 0, stream>>>(x, Ws1, Wn1, selfo, t1, N);
    agg64_kernel<<<B, 512, 0, stream>>>(epart, bucket_cnt, t1, selfo, b1, h1, N);
    gemm2_kernel<<<(N + 127) / 128, 256, 0, stream>>>(h1, Ws2, Wn2, outp, t2, N);
    agg16_kernel<<<B, 512, 0, stream>>>(epart, bucket_cnt, t2, b2, outp, N);
}

// Round 10
// 169.719 us; speedup vs baseline: 3.3662x; 3.3662x over previous
//
#include <hip/hip_runtime.h>
#include <hip/hip_bf16.h>
#include <cstring>

// GraphSAGE 2-layer, CSR-gather formulation (no float atomics).
//   h1 = relu(x@Ws1 + mean_agg(x)@Wn1 + b1)
//   out = h1@Ws2 + mean_agg(h1)@Wn2 + b2
// mean_agg(h)@W == mean_agg(h@W): project first, then aggregate projected rows.
// CSR via fixed-capacity bucket sort (partition -> per-bucket LDS buildcsr).
// R9's LDS-atomic aggregation FAILED (356 us: 64 serialized LDS atomics/edge,
// 196-block grid): aggregation stays as register-accumulating gathers.
// selfo/t1/h1/t2 all bf16 (fp32 accumulation everywhere).

#define FEATS 64
#define CLS   16
#define EPT   16      // edges/thread in partition kernel (4096 edges/block)
#define CAP   5120    // bucket capacity; mean 4081 edges/bucket, 16 sigma margin

typedef unsigned short bf16_t;

__device__ __forceinline__ float bfbits2f(unsigned lo16) {
    unsigned v = lo16 << 16;
    float f;
    __builtin_memcpy(&f, &v, 4);
    return f;
}
__device__ __forceinline__ bf16_t f2bf(float f) {
    unsigned u;
    __builtin_memcpy(&u, &f, 4);
    u = (u + 0x7FFFu + ((u >> 16) & 1u)) >> 16;   // round-to-nearest-even
    return (bf16_t)u;
}
__device__ __forceinline__ unsigned pack2(float a, float b) {
    return (unsigned)f2bf(a) | ((unsigned)f2bf(b) << 16);
}

// ---------------- partition: scatter packed (src<<8)|(dst&255) into fixed-cap buckets ----------------
__global__ __launch_bounds__(256) void partition_kernel(const int* __restrict__ src,
                                                        const int* __restrict__ dst,
                                                        int* __restrict__ bucket_cnt,
                                                        int* __restrict__ epart, int E) {
    __shared__ int hist[256];
    __shared__ int base[256];
    int t = threadIdx.x;
    int e0 = blockIdx.x * (256 * EPT);
    hist[t] = 0;
    __syncthreads();
    int pk[EPT];
    int bk[EPT];
#pragma unroll
    for (int j = 0; j < EPT; ++j) {
        int e = e0 + j * 256 + t;
        if (e < E) {
            int d = dst[e];
            pk[j] = (src[e] << 8) | (d & 255);
            bk[j] = d >> 8;
            atomicAdd(&hist[bk[j]], 1);
        } else bk[j] = -1;
    }
    __syncthreads();
    int c = hist[t];
    if (c) base[t] = atomicAdd(&bucket_cnt[t], c);
    hist[t] = 0;
    __syncthreads();
#pragma unroll
    for (int j = 0; j < EPT; ++j) {
        if (bk[j] >= 0) {
            int r = atomicAdd(&hist[bk[j]], 1);
            epart[bk[j] * CAP + base[bk[j]] + r] = pk[j];
        }
    }
}

// ---------------- per-bucket CSR build, all bookkeeping in LDS ----------------
// block b: nodes [b*256, b*256+256), edges epart[b*CAP .. b*CAP+bucket_cnt[b])
__global__ __launch_bounds__(256) void buildcsr_kernel(const int* __restrict__ epart,
                                                       const int* __restrict__ bucket_cnt,
                                                       int* __restrict__ row_start,
                                                       unsigned short* __restrict__ deg16,
                                                       int* __restrict__ csr, int N) {
    __shared__ int cnt[256];
    __shared__ int pref[256];
    __shared__ int s[256];
    int t = threadIdx.x;
    int b = blockIdx.x;
    int ebeg = b * CAP;
    int ecnt = bucket_cnt[b];
    cnt[t] = 0;
    __syncthreads();
    for (int e = t; e < ecnt; e += 256)
        atomicAdd(&cnt[epart[ebeg + e] & 255], 1);
    __syncthreads();
    int v = cnt[t];
    s[t] = v;
    __syncthreads();
    for (int off = 1; off < 256; off <<= 1) {
        int u = (t >= off) ? s[t - off] : 0;
        __syncthreads();
        s[t] += u;
        __syncthreads();
    }
    pref[t] = s[t] - v;
    int node = b * 256 + t;
    if (node < N) {
        row_start[node] = ebeg + pref[t];
        deg16[node] = (unsigned short)v;
    }
    cnt[t] = 0;
    __syncthreads();
    for (int e = t; e < ecnt; e += 256) {
        int pk = epart[ebeg + e];
        int ln = pk & 255;
        int r = atomicAdd(&cnt[ln], 1);
        csr[ebeg + pref[ln] + r] = pk >> 8;
    }
}

// ---------------- GEMM1: [N,64] x [64,128] -> selfo [N,64] bf16, t1 [N,64] bf16 ----------------
__global__ __launch_bounds__(256) void gemm1_kernel(
    const float* __restrict__ x, const float* __restrict__ Ws,
    const float* __restrict__ Wn, bf16_t* __restrict__ selfo,
    bf16_t* __restrict__ t1, int N)
{
    __shared__ float Wc[64 * 128];   // 32 KB
    __shared__ float xs[128 * 65];   // 33.3 KB
    int t = threadIdx.x;
    int node0 = blockIdx.x * 128;

    for (int idx = t; idx < 64 * 128; idx += 256) {
        int k = idx >> 7, c = idx & 127;
        Wc[idx] = (c < 64) ? Ws[k * 64 + c] : Wn[k * 64 + (c - 64)];
    }
    for (int idx = t; idx < 128 * 16; idx += 256) {
        int row = idx >> 4, c4 = idx & 15;
        int node = node0 + row;
        float4 v = (node < N) ? ((const float4*)(x + (size_t)node * 64))[c4]
                              : make_float4(0.f, 0.f, 0.f, 0.f);
        float* p = &xs[row * 65 + c4 * 4];
        p[0] = v.x; p[1] = v.y; p[2] = v.z; p[3] = v.w;
    }
    __syncthreads();

    int m = t & 31;
    int g = t >> 5;            // 8 col-groups of 16
    float acc[4][16];
#pragma unroll
    for (int j = 0; j < 4; ++j)
#pragma unroll
        for (int c = 0; c < 16; ++c) acc[j][c] = 0.f;

    for (int k = 0; k < 64; ++k) {
        float w[16];
        const float* wp = &Wc[k * 128 + g * 16];
#pragma unroll
        for (int c = 0; c < 16; ++c) w[c] = wp[c];
        float a0 = xs[m * 65 + k];
        float a1 = xs[(m + 32) * 65 + k];
        float a2 = xs[(m + 64) * 65 + k];
        float a3 = xs[(m + 96) * 65 + k];
#pragma unroll
        for (int c = 0; c < 16; ++c) {
            acc[0][c] += a0 * w[c];
            acc[1][c] += a1 * w[c];
            acc[2][c] += a2 * w[c];
            acc[3][c] += a3 * w[c];
        }
    }
#pragma unroll
    for (int j = 0; j < 4; ++j) {
        int node = node0 + m + 32 * j;
        if (node < N) {
            bf16_t* dstp = ((g < 4) ? selfo : t1) + (size_t)node * 64 + (g & 3) * 16;
            uint4 p0, p1;
            p0.x = pack2(acc[j][0],  acc[j][1]);  p0.y = pack2(acc[j][2],  acc[j][3]);
            p0.z = pack2(acc[j][4],  acc[j][5]);  p0.w = pack2(acc[j][6],  acc[j][7]);
            p1.x = pack2(acc[j][8],  acc[j][9]);  p1.y = pack2(acc[j][10], acc[j][11]);
            p1.z = pack2(acc[j][12], acc[j][13]); p1.w = pack2(acc[j][14], acc[j][15]);
            *(uint4*)(dstp) = p0;
            *(uint4*)(dstp + 8) = p1;
        }
    }
}

// ---------------- gather64: h1 = relu(selfo + (sum t1[src])/deg + b1), bf16 in/out ----------------
// one wave per node; lane = (eslot, cg): 4 edge slots x 16 col-groups (uint2 = 4 bf16 each).
__global__ __launch_bounds__(256) void gather64_kernel(
    const int* __restrict__ csr, const int* __restrict__ row_start,
    const unsigned short* __restrict__ deg16,
    const bf16_t* __restrict__ t1, const bf16_t* __restrict__ selfo,
    bf16_t* __restrict__ h1, const float* __restrict__ b1, int N)
{
    int wid = (blockIdx.x * 256 + threadIdx.x) >> 6;
    int lane = threadIdx.x & 63;
    int eslot = lane >> 4;       // 0..3
    int cg = lane & 15;          // cols [cg*4, cg*4+4)
    if (wid >= N) return;
    int beg = row_start[wid];
    int d = deg16[wid];
    float ax = 0.f, ay = 0.f, az = 0.f, aw = 0.f;
    int i = eslot;
    for (; i + 12 < d; i += 16) {
        int s0 = csr[beg + i];
        int s1 = csr[beg + i + 4];
        int s2 = csr[beg + i + 8];
        int s3 = csr[beg + i + 12];
        uint2 r0 = *(const uint2*)(t1 + (size_t)s0 * 64 + cg * 4);
        uint2 r1 = *(const uint2*)(t1 + (size_t)s1 * 64 + cg * 4);
        uint2 r2 = *(const uint2*)(t1 + (size_t)s2 * 64 + cg * 4);
        uint2 r3 = *(const uint2*)(t1 + (size_t)s3 * 64 + cg * 4);
        ax += bfbits2f(r0.x & 0xffff) + bfbits2f(r1.x & 0xffff)
            + bfbits2f(r2.x & 0xffff) + bfbits2f(r3.x & 0xffff);
        ay += bfbits2f(r0.x >> 16) + bfbits2f(r1.x >> 16)
            + bfbits2f(r2.x >> 16) + bfbits2f(r3.x >> 16);
        az += bfbits2f(r0.y & 0xffff) + bfbits2f(r1.y & 0xffff)
            + bfbits2f(r2.y & 0xffff) + bfbits2f(r3.y & 0xffff);
        aw += bfbits2f(r0.y >> 16) + bfbits2f(r1.y >> 16)
            + bfbits2f(r2.y >> 16) + bfbits2f(r3.y >> 16);
    }
    for (; i < d; i += 4) {
        int s0 = csr[beg + i];
        uint2 r0 = *(const uint2*)(t1 + (size_t)s0 * 64 + cg * 4);
        ax += bfbits2f(r0.x & 0xffff);
        ay += bfbits2f(r0.x >> 16);
        az += bfbits2f(r0.y & 0xffff);
        aw += bfbits2f(r0.y >> 16);
    }
    // reduce across the 4 edge slots (lanes differing by 16 and 32)
    ax += __shfl_xor(ax, 16); ay += __shfl_xor(ay, 16);
    az += __shfl_xor(az, 16); aw += __shfl_xor(aw, 16);
    ax += __shfl_xor(ax, 32); ay += __shfl_xor(ay, 32);
    az += __shfl_xor(az, 32); aw += __shfl_xor(aw, 32);
    if (eslot == 0) {
        float inv = 1.f / fmaxf((float)d, 1.f);
        size_t o = (size_t)wid * 64 + cg * 4;
        uint2 su = *(const uint2*)(selfo + o);
        float4 bb = *(const float4*)(b1 + cg * 4);
        float rx = fmaxf(bfbits2f(su.x & 0xffff) + ax * inv + bb.x, 0.f);
        float ry = fmaxf(bfbits2f(su.x >> 16)    + ay * inv + bb.y, 0.f);
        float rz = fmaxf(bfbits2f(su.y & 0xffff) + az * inv + bb.z, 0.f);
        float rw = fmaxf(bfbits2f(su.y >> 16)    + aw * inv + bb.w, 0.f);
        uint2 pk;
        pk.x = pack2(rx, ry);
        pk.y = pack2(rz, rw);
        *(uint2*)(h1 + o) = pk;
    }
}

// ---------------- GEMM2: h1(bf16) [N,64] x [64,32] -> out(self) [N,16] f32, t2 [N,16] bf16 ----------------
__global__ __launch_bounds__(256) void gemm2_kernel(
    const bf16_t* __restrict__ h1, const float* __restrict__ Ws,
    const float* __restrict__ Wn, float* __restrict__ outp,
    bf16_t* __restrict__ t2, int N)
{
    __shared__ float Wc[64 * 32];    // 8 KB
    __shared__ float xs[128 * 65];   // 33.3 KB
    int t = threadIdx.x;
    int node0 = blockIdx.x * 128;

    for (int idx = t; idx < 64 * 32; idx += 256) {
        int k = idx >> 5, c = idx & 31;
        Wc[idx] = (c < 16) ? Ws[k * 16 + c] : Wn[k * 16 + (c - 16)];
    }
    for (int idx = t; idx < 128 * 8; idx += 256) {
        int row = idx >> 3, c8 = idx & 7;
        int node = node0 + row;
        float* p = &xs[row * 65 + c8 * 8];
        if (node < N) {
            uint4 u = *(const uint4*)(h1 + (size_t)node * 64 + c8 * 8);
            p[0] = bfbits2f(u.x & 0xffff); p[1] = bfbits2f(u.x >> 16);
            p[2] = bfbits2f(u.y & 0xffff); p[3] = bfbits2f(u.y >> 16);
            p[4] = bfbits2f(u.z & 0xffff); p[5] = bfbits2f(u.z >> 16);
            p[6] = bfbits2f(u.w & 0xffff); p[7] = bfbits2f(u.w >> 16);
        } else {
            for (int qq = 0; qq < 8; ++qq) p[qq] = 0.f;
        }
    }
    __syncthreads();

    int m = t & 31;
    int g = t >> 5;            // 8 col-groups of 4
    float acc[4][4];
#pragma unroll
    for (int j = 0; j < 4; ++j)
#pragma unroll
        for (int c = 0; c < 4; ++c) acc[j][c] = 0.f;

    for (int k = 0; k < 64; ++k) {
        float w[4];
        const float* wp = &Wc[k * 32 + g * 4];
#pragma unroll
        for (int c = 0; c < 4; ++c) w[c] = wp[c];
        float a0 = xs[m * 65 + k];
        float a1 = xs[(m + 32) * 65 + k];
        float a2 = xs[(m + 64) * 65 + k];
        float a3 = xs[(m + 96) * 65 + k];
#pragma unroll
        for (int c = 0; c < 4; ++c) {
            acc[0][c] += a0 * w[c];
            acc[1][c] += a1 * w[c];
            acc[2][c] += a2 * w[c];
            acc[3][c] += a3 * w[c];
        }
    }
#pragma unroll
    for (int j = 0; j < 4; ++j) {
        int node = node0 + m + 32 * j;
        if (node < N) {
            if (g < 4) {
                *(float4*)(outp + (size_t)node * 16 + g * 4) =
                    make_float4(acc[j][0], acc[j][1], acc[j][2], acc[j][3]);
            } else {
                uint2 pk;
                pk.x = pack2(acc[j][0], acc[j][1]);
                pk.y = pack2(acc[j][2], acc[j][3]);
                *(uint2*)(t2 + (size_t)node * 16 + (g - 4) * 4) = pk;
            }
        }
    }
}

// ---------------- gather16: out += (sum t2[src])/deg + b2 ----------------
// 8 threads per node, each handles 2 cols (uint loads), 4x unroll.
__global__ __launch_bounds__(256) void gather16_kernel(
    const int* __restrict__ csr, const int* __restrict__ row_start,
    const unsigned short* __restrict__ deg16,
    const bf16_t* __restrict__ t2,
    float* __restrict__ outp, const float* __restrict__ b2, int N)
{
    int gt = blockIdx.x * 256 + threadIdx.x;
    int node = gt >> 3;
    int c2 = gt & 7;             // cols [c2*2, c2*2+2)
    if (node >= N) return;
    int beg = row_start[node];
    int d = deg16[node];
    int end = beg + d;
    float a0 = 0.f, a1 = 0.f;
    int i = beg;
    for (; i + 4 <= end; i += 4) {
        int s0 = csr[i], s1 = csr[i + 1], s2 = csr[i + 2], s3 = csr[i + 3];
        unsigned u0 = *(const unsigned*)(t2 + (size_t)s0 * 16 + c2 * 2);
        unsigned u1 = *(const unsigned*)(t2 + (size_t)s1 * 16 + c2 * 2);
        unsigned u2 = *(const unsigned*)(t2 + (size_t)s2 * 16 + c2 * 2);
        unsigned u3 = *(const unsigned*)(t2 + (size_t)s3 * 16 + c2 * 2);
        a0 += bfbits2f(u0 & 0xffff) + bfbits2f(u1 & 0xffff)
            + bfbits2f(u2 & 0xffff) + bfbits2f(u3 & 0xffff);
        a1 += bfbits2f(u0 >> 16) + bfbits2f(u1 >> 16)
            + bfbits2f(u2 >> 16) + bfbits2f(u3 >> 16);
    }
    for (; i < end; ++i) {
        int s = csr[i];
        unsigned u = *(const unsigned*)(t2 + (size_t)s * 16 + c2 * 2);
        a0 += bfbits2f(u & 0xffff);
        a1 += bfbits2f(u >> 16);
    }
    float inv = 1.f / fmaxf((float)d, 1.f);
    size_t o = (size_t)node * 16 + c2 * 2;
    outp[o]     += a0 * inv + b2[c2 * 2];
    outp[o + 1] += a1 * inv + b2[c2 * 2 + 1];
}

extern "C" void kernel_launch(void* const* d_in, const int* in_sizes, int n_in,
                              void* d_out, int out_size, void* d_ws, size_t ws_size,
                              hipStream_t stream) {
    const float* x   = (const float*)d_in[0];
    const int*   src = (const int*)d_in[1];
    const int*   dst = (const int*)d_in[2];
    const float* Ws1 = (const float*)d_in[3];
    const float* Wn1 = (const float*)d_in[4];
    const float* b1  = (const float*)d_in[5];
    const float* Ws2 = (const float*)d_in[6];
    const float* Wn2 = (const float*)d_in[7];
    const float* b2  = (const float*)d_in[8];
    float* outp = (float*)d_out;

    const int N = in_sizes[0] / FEATS;   // 50000
    const int E = in_sizes[1];           // 800000
    const int B = (N + 255) / 256;       // buckets (196) — must be <= 256

    // workspace: bucket_cnt[256] | epart[B*CAP] | csr[B*CAP] | row_start[N] |
    // deg16[N] u16 | selfo bf16[N*64] | t1 bf16[N*64] | h1 bf16[N*64] | t2 bf16[N*16]
    char* p = (char*)d_ws;
    auto align16 = [](char* q) { return (char*)(((size_t)q + 15) & ~(size_t)15); };
    int* bucket_cnt    = (int*)p;                  p = (char*)(bucket_cnt + 256);
    int* epart         = (int*)p;                  p = (char*)(epart + (size_t)B * CAP);
    int* csr           = (int*)p;                  p = (char*)(csr + (size_t)B * CAP);
    int* row_start     = (int*)align16(p);         p = (char*)(row_start + N);
    unsigned short* deg16 = (unsigned short*)align16(p); p = (char*)(deg16 + N);
    bf16_t* selfo      = (bf16_t*)align16(p);      p = (char*)(selfo + (size_t)N * 64);
    bf16_t* t1         = (bf16_t*)align16(p);      p = (char*)(t1 + (size_t)N * 64);
    bf16_t* h1         = (bf16_t*)align16(p);      p = (char*)(h1 + (size_t)N * 64);
    bf16_t* t2         = (bf16_t*)align16(p);

    hipMemsetAsync(bucket_cnt, 0, 256 * sizeof(int), stream);

    partition_kernel<<<(E + 256 * EPT - 1) / (256 * EPT), 256, 0, stream>>>(
        src, dst, bucket_cnt, epart, E);
    buildcsr_kernel<<<B, 256, 0, stream>>>(epart, bucket_cnt, row_start, deg16, csr, N);

    gemm1_kernel<<<(N + 127) / 128, 256, 0, stream>>>(x, Ws1, Wn1, selfo, t1, N);
    gather64_kernel<<<((size_t)N * 64 + 255) / 256, 256, 0, stream>>>(
        csr, row_start, deg16, t1, selfo, h1, b1, N);
    gemm2_kernel<<<(N + 127) / 128, 256, 0, stream>>>(h1, Ws2, Wn2, outp, t2, N);
    gather16_kernel<<<((size_t)N * 8 + 255) / 256, 256, 0, stream>>>(
        csr, row_start, deg16, t2, outp, b2, N);
}

// Round 11
// 165.761 us; speedup vs baseline: 3.4466x; 1.0239x over previous
//
#include <hip/hip_runtime.h>
#include <hip/hip_bf16.h>
#include <cstring>

// GraphSAGE 2-layer, CSR-gather formulation (no float atomics).
//   h1 = relu(x@Ws1 + mean_agg(x)@Wn1 + b1)
//   out = h1@Ws2 + mean_agg(h1)@Wn2 + b2
// mean_agg(h)@W == mean_agg(h@W): project first, then aggregate projected rows.
// CSR via fixed-capacity bucket sort (partition -> per-bucket LDS buildcsr).
// t1 (the randomly-gathered layer-1 table) is fp8 e4m3: 3.2 MB < 4 MB per-XCD
// L2 -> gather64 runs L2-hit instead of thrashing (was 6.4 MB bf16, ~62% hit).
// HW v_cvt_pk_fp8 used for pack/unpack. selfo/h1/t2 bf16; fp32 accumulation.
// R9 lesson: LDS float atomics for aggregation = 356 us disaster; gathers stay
// register-accumulating.

#define FEATS 64
#define CLS   16
#define EPT   16      // edges/thread in partition kernel (4096 edges/block)
#define CAP   5120    // bucket capacity; mean 4081 edges/bucket, 16 sigma margin

typedef unsigned short bf16_t;
typedef float floatx2 __attribute__((ext_vector_type(2)));

__device__ __forceinline__ float bfbits2f(unsigned lo16) {
    unsigned v = lo16 << 16;
    float f;
    __builtin_memcpy(&f, &v, 4);
    return f;
}
__device__ __forceinline__ bf16_t f2bf(float f) {
    unsigned u;
    __builtin_memcpy(&u, &f, 4);
    u = (u + 0x7FFFu + ((u >> 16) & 1u)) >> 16;   // round-to-nearest-even
    return (bf16_t)u;
}
__device__ __forceinline__ unsigned pack2(float a, float b) {
    return (unsigned)f2bf(a) | ((unsigned)f2bf(b) << 16);
}
// pack 4 f32 -> 4 fp8 e4m3 in one dword (HW cvt, RNE)
__device__ __forceinline__ unsigned pack4_fp8(float a, float b, float c, float d) {
    int q = __builtin_amdgcn_cvt_pk_fp8_f32(a, b, 0, false);
    q = __builtin_amdgcn_cvt_pk_fp8_f32(c, d, q, true);
    return (unsigned)q;
}

// ---------------- partition: scatter packed (src<<8)|(dst&255) into fixed-cap buckets ----------------
__global__ __launch_bounds__(256) void partition_kernel(const int* __restrict__ src,
                                                        const int* __restrict__ dst,
                                                        int* __restrict__ bucket_cnt,
                                                        int* __restrict__ epart, int E) {
    __shared__ int hist[256];
    __shared__ int base[256];
    int t = threadIdx.x;
    int e0 = blockIdx.x * (256 * EPT);
    hist[t] = 0;
    __syncthreads();
    int pk[EPT];
    int bk[EPT];
#pragma unroll
    for (int j = 0; j < EPT; ++j) {
        int e = e0 + j * 256 + t;
        if (e < E) {
            int d = dst[e];
            pk[j] = (src[e] << 8) | (d & 255);
            bk[j] = d >> 8;
            atomicAdd(&hist[bk[j]], 1);
        } else bk[j] = -1;
    }
    __syncthreads();
    int c = hist[t];
    if (c) base[t] = atomicAdd(&bucket_cnt[t], c);
    hist[t] = 0;
    __syncthreads();
#pragma unroll
    for (int j = 0; j < EPT; ++j) {
        if (bk[j] >= 0) {
            int r = atomicAdd(&hist[bk[j]], 1);
            epart[bk[j] * CAP + base[bk[j]] + r] = pk[j];
        }
    }
}

// ---------------- per-bucket CSR build, all bookkeeping in LDS ----------------
__global__ __launch_bounds__(256) void buildcsr_kernel(const int* __restrict__ epart,
                                                       const int* __restrict__ bucket_cnt,
                                                       int* __restrict__ row_start,
                                                       unsigned short* __restrict__ deg16,
                                                       int* __restrict__ csr, int N) {
    __shared__ int cnt[256];
    __shared__ int pref[256];
    __shared__ int s[256];
    int t = threadIdx.x;
    int b = blockIdx.x;
    int ebeg = b * CAP;
    int ecnt = bucket_cnt[b];
    cnt[t] = 0;
    __syncthreads();
    for (int e = t; e < ecnt; e += 256)
        atomicAdd(&cnt[epart[ebeg + e] & 255], 1);
    __syncthreads();
    int v = cnt[t];
    s[t] = v;
    __syncthreads();
    for (int off = 1; off < 256; off <<= 1) {
        int u = (t >= off) ? s[t - off] : 0;
        __syncthreads();
        s[t] += u;
        __syncthreads();
    }
    pref[t] = s[t] - v;
    int node = b * 256 + t;
    if (node < N) {
        row_start[node] = ebeg + pref[t];
        deg16[node] = (unsigned short)v;
    }
    cnt[t] = 0;
    __syncthreads();
    for (int e = t; e < ecnt; e += 256) {
        int pk = epart[ebeg + e];
        int ln = pk & 255;
        int r = atomicAdd(&cnt[ln], 1);
        csr[ebeg + pref[ln] + r] = pk >> 8;
    }
}

// ---------------- GEMM1: [N,64] x [64,128] -> selfo [N,64] bf16, t1 [N,64] fp8 ----------------
__global__ __launch_bounds__(256) void gemm1_kernel(
    const float* __restrict__ x, const float* __restrict__ Ws,
    const float* __restrict__ Wn, bf16_t* __restrict__ selfo,
    unsigned char* __restrict__ t1, int N)
{
    __shared__ float Wc[64 * 128];   // 32 KB
    __shared__ float xs[128 * 65];   // 33.3 KB
    int t = threadIdx.x;
    int node0 = blockIdx.x * 128;

    for (int idx = t; idx < 64 * 128; idx += 256) {
        int k = idx >> 7, c = idx & 127;
        Wc[idx] = (c < 64) ? Ws[k * 64 + c] : Wn[k * 64 + (c - 64)];
    }
    for (int idx = t; idx < 128 * 16; idx += 256) {
        int row = idx >> 4, c4 = idx & 15;
        int node = node0 + row;
        float4 v = (node < N) ? ((const float4*)(x + (size_t)node * 64))[c4]
                              : make_float4(0.f, 0.f, 0.f, 0.f);
        float* p = &xs[row * 65 + c4 * 4];
        p[0] = v.x; p[1] = v.y; p[2] = v.z; p[3] = v.w;
    }
    __syncthreads();

    int m = t & 31;
    int g = t >> 5;            // 8 col-groups of 16
    float acc[4][16];
#pragma unroll
    for (int j = 0; j < 4; ++j)
#pragma unroll
        for (int c = 0; c < 16; ++c) acc[j][c] = 0.f;

    for (int k = 0; k < 64; ++k) {
        float w[16];
        const float* wp = &Wc[k * 128 + g * 16];
#pragma unroll
        for (int c = 0; c < 16; ++c) w[c] = wp[c];
        float a0 = xs[m * 65 + k];
        float a1 = xs[(m + 32) * 65 + k];
        float a2 = xs[(m + 64) * 65 + k];
        float a3 = xs[(m + 96) * 65 + k];
#pragma unroll
        for (int c = 0; c < 16; ++c) {
            acc[0][c] += a0 * w[c];
            acc[1][c] += a1 * w[c];
            acc[2][c] += a2 * w[c];
            acc[3][c] += a3 * w[c];
        }
    }
#pragma unroll
    for (int j = 0; j < 4; ++j) {
        int node = node0 + m + 32 * j;
        if (node < N) {
            if (g < 4) {
                bf16_t* dstp = selfo + (size_t)node * 64 + g * 16;
                uint4 p0, p1;
                p0.x = pack2(acc[j][0],  acc[j][1]);  p0.y = pack2(acc[j][2],  acc[j][3]);
                p0.z = pack2(acc[j][4],  acc[j][5]);  p0.w = pack2(acc[j][6],  acc[j][7]);
                p1.x = pack2(acc[j][8],  acc[j][9]);  p1.y = pack2(acc[j][10], acc[j][11]);
                p1.z = pack2(acc[j][12], acc[j][13]); p1.w = pack2(acc[j][14], acc[j][15]);
                *(uint4*)(dstp) = p0;
                *(uint4*)(dstp + 8) = p1;
            } else {
                unsigned char* dstp = t1 + (size_t)node * 64 + (g - 4) * 16;
                uint4 q;
                q.x = pack4_fp8(acc[j][0],  acc[j][1],  acc[j][2],  acc[j][3]);
                q.y = pack4_fp8(acc[j][4],  acc[j][5],  acc[j][6],  acc[j][7]);
                q.z = pack4_fp8(acc[j][8],  acc[j][9],  acc[j][10], acc[j][11]);
                q.w = pack4_fp8(acc[j][12], acc[j][13], acc[j][14], acc[j][15]);
                *(uint4*)(dstp) = q;
            }
        }
    }
}

// ---------------- gather64: h1 = relu(selfo + (sum t1[src])/deg + b1) ----------------
// one wave per node; lane = (eslot, cg): 4 edge slots x 16 col-groups.
// t1 rows are 64 fp8 (64 B): each lane loads 1 dword = 4 fp8, HW-decodes.
__global__ __launch_bounds__(256) void gather64_kernel(
    const int* __restrict__ csr, const int* __restrict__ row_start,
    const unsigned short* __restrict__ deg16,
    const unsigned char* __restrict__ t1, const bf16_t* __restrict__ selfo,
    bf16_t* __restrict__ h1, const float* __restrict__ b1, int N)
{
    int wid = (blockIdx.x * 256 + threadIdx.x) >> 6;
    int lane = threadIdx.x & 63;
    int eslot = lane >> 4;       // 0..3
    int cg = lane & 15;          // cols [cg*4, cg*4+4)
    if (wid >= N) return;
    int beg = row_start[wid];
    int d = deg16[wid];
    float ax = 0.f, ay = 0.f, az = 0.f, aw = 0.f;
    int i = eslot;
    for (; i + 12 < d; i += 16) {
        int s0 = csr[beg + i];
        int s1 = csr[beg + i + 4];
        int s2 = csr[beg + i + 8];
        int s3 = csr[beg + i + 12];
        unsigned r0 = *(const unsigned*)(t1 + (size_t)s0 * 64 + cg * 4);
        unsigned r1 = *(const unsigned*)(t1 + (size_t)s1 * 64 + cg * 4);
        unsigned r2 = *(const unsigned*)(t1 + (size_t)s2 * 64 + cg * 4);
        unsigned r3 = *(const unsigned*)(t1 + (size_t)s3 * 64 + cg * 4);
        floatx2 p0 = __builtin_amdgcn_cvt_pk_f32_fp8((int)r0, false);
        floatx2 q0 = __builtin_amdgcn_cvt_pk_f32_fp8((int)r0, true);
        floatx2 p1 = __builtin_amdgcn_cvt_pk_f32_fp8((int)r1, false);
        floatx2 q1 = __builtin_amdgcn_cvt_pk_f32_fp8((int)r1, true);
        floatx2 p2 = __builtin_amdgcn_cvt_pk_f32_fp8((int)r2, false);
        floatx2 q2 = __builtin_amdgcn_cvt_pk_f32_fp8((int)r2, true);
        floatx2 p3 = __builtin_amdgcn_cvt_pk_f32_fp8((int)r3, false);
        floatx2 q3 = __builtin_amdgcn_cvt_pk_f32_fp8((int)r3, true);
        ax += p0.x + p1.x + p2.x + p3.x;
        ay += p0.y + p1.y + p2.y + p3.y;
        az += q0.x + q1.x + q2.x + q3.x;
        aw += q0.y + q1.y + q2.y + q3.y;
    }
    for (; i < d; i += 4) {
        int s0 = csr[beg + i];
        unsigned r0 = *(const unsigned*)(t1 + (size_t)s0 * 64 + cg * 4);
        floatx2 p0 = __builtin_amdgcn_cvt_pk_f32_fp8((int)r0, false);
        floatx2 q0 = __builtin_amdgcn_cvt_pk_f32_fp8((int)r0, true);
        ax += p0.x; ay += p0.y; az += q0.x; aw += q0.y;
    }
    // reduce across the 4 edge slots (lanes differing by 16 and 32)
    ax += __shfl_xor(ax, 16); ay += __shfl_xor(ay, 16);
    az += __shfl_xor(az, 16); aw += __shfl_xor(aw, 16);
    ax += __shfl_xor(ax, 32); ay += __shfl_xor(ay, 32);
    az += __shfl_xor(az, 32); aw += __shfl_xor(aw, 32);
    if (eslot == 0) {
        float inv = 1.f / fmaxf((float)d, 1.f);
        size_t o = (size_t)wid * 64 + cg * 4;
        uint2 su = *(const uint2*)(selfo + o);
        float4 bb = *(const float4*)(b1 + cg * 4);
        float rx = fmaxf(bfbits2f(su.x & 0xffff) + ax * inv + bb.x, 0.f);
        float ry = fmaxf(bfbits2f(su.x >> 16)    + ay * inv + bb.y, 0.f);
        float rz = fmaxf(bfbits2f(su.y & 0xffff) + az * inv + bb.z, 0.f);
        float rw = fmaxf(bfbits2f(su.y >> 16)    + aw * inv + bb.w, 0.f);
        uint2 pk;
        pk.x = pack2(rx, ry);
        pk.y = pack2(rz, rw);
        *(uint2*)(h1 + o) = pk;
    }
}

// ---------------- GEMM2: h1(bf16) [N,64] x [64,32] -> out(self) [N,16] f32, t2 [N,16] bf16 ----------------
__global__ __launch_bounds__(256) void gemm2_kernel(
    const bf16_t* __restrict__ h1, const float* __restrict__ Ws,
    const float* __restrict__ Wn, float* __restrict__ outp,
    bf16_t* __restrict__ t2, int N)
{
    __shared__ float Wc[64 * 32];    // 8 KB
    __shared__ float xs[128 * 65];   // 33.3 KB
    int t = threadIdx.x;
    int node0 = blockIdx.x * 128;

    for (int idx = t; idx < 64 * 32; idx += 256) {
        int k = idx >> 5, c = idx & 31;
        Wc[idx] = (c < 16) ? Ws[k * 16 + c] : Wn[k * 16 + (c - 16)];
    }
    for (int idx = t; idx < 128 * 8; idx += 256) {
        int row = idx >> 3, c8 = idx & 7;
        int node = node0 + row;
        float* p = &xs[row * 65 + c8 * 8];
        if (node < N) {
            uint4 u = *(const uint4*)(h1 + (size_t)node * 64 + c8 * 8);
            p[0] = bfbits2f(u.x & 0xffff); p[1] = bfbits2f(u.x >> 16);
            p[2] = bfbits2f(u.y & 0xffff); p[3] = bfbits2f(u.y >> 16);
            p[4] = bfbits2f(u.z & 0xffff); p[5] = bfbits2f(u.z >> 16);
            p[6] = bfbits2f(u.w & 0xffff); p[7] = bfbits2f(u.w >> 16);
        } else {
            for (int qq = 0; qq < 8; ++qq) p[qq] = 0.f;
        }
    }
    __syncthreads();

    int m = t & 31;
    int g = t >> 5;            // 8 col-groups of 4
    float acc[4][4];
#pragma unroll
    for (int j = 0; j < 4; ++j)
#pragma unroll
        for (int c = 0; c < 4; ++c) acc[j][c] = 0.f;

    for (int k = 0; k < 64; ++k) {
        float w[4];
        const float* wp = &Wc[k * 32 + g * 4];
#pragma unroll
        for (int c = 0; c < 4; ++c) w[c] = wp[c];
        float a0 = xs[m * 65 + k];
        float a1 = xs[(m + 32) * 65 + k];
        float a2 = xs[(m + 64) * 65 + k];
        float a3 = xs[(m + 96) * 65 + k];
#pragma unroll
        for (int c = 0; c < 4; ++c) {
            acc[0][c] += a0 * w[c];
            acc[1][c] += a1 * w[c];
            acc[2][c] += a2 * w[c];
            acc[3][c] += a3 * w[c];
        }
    }
#pragma unroll
    for (int j = 0; j < 4; ++j) {
        int node = node0 + m + 32 * j;
        if (node < N) {
            if (g < 4) {
                *(float4*)(outp + (size_t)node * 16 + g * 4) =
                    make_float4(acc[j][0], acc[j][1], acc[j][2], acc[j][3]);
            } else {
                uint2 pk;
                pk.x = pack2(acc[j][0], acc[j][1]);
                pk.y = pack2(acc[j][2], acc[j][3]);
                *(uint2*)(t2 + (size_t)node * 16 + (g - 4) * 4) = pk;
            }
        }
    }
}

// ---------------- gather16: out += (sum t2[src])/deg + b2 ----------------
__global__ __launch_bounds__(256) void gather16_kernel(
    const int* __restrict__ csr, const int* __restrict__ row_start,
    const unsigned short* __restrict__ deg16,
    const bf16_t* __restrict__ t2,
    float* __restrict__ outp, const float* __restrict__ b2, int N)
{
    int gt = blockIdx.x * 256 + threadIdx.x;
    int node = gt >> 3;
    int c2 = gt & 7;             // cols [c2*2, c2*2+2)
    if (node >= N) return;
    int beg = row_start[node];
    int d = deg16[node];
    int end = beg + d;
    float a0 = 0.f, a1 = 0.f;
    int i = beg;
    for (; i + 4 <= end; i += 4) {
        int s0 = csr[i], s1 = csr[i + 1], s2 = csr[i + 2], s3 = csr[i + 3];
        unsigned u0 = *(const unsigned*)(t2 + (size_t)s0 * 16 + c2 * 2);
        unsigned u1 = *(const unsigned*)(t2 + (size_t)s1 * 16 + c2 * 2);
        unsigned u2 = *(const unsigned*)(t2 + (size_t)s2 * 16 + c2 * 2);
        unsigned u3 = *(const unsigned*)(t2 + (size_t)s3 * 16 + c2 * 2);
        a0 += bfbits2f(u0 & 0xffff) + bfbits2f(u1 & 0xffff)
            + bfbits2f(u2 & 0xffff) + bfbits2f(u3 & 0xffff);
        a1 += bfbits2f(u0 >> 16) + bfbits2f(u1 >> 16)
            + bfbits2f(u2 >> 16) + bfbits2f(u3 >> 16);
    }
    for (; i < end; ++i) {
        int s = csr[i];
        unsigned u = *(const unsigned*)(t2 + (size_t)s * 16 + c2 * 2);
        a0 += bfbits2f(u & 0xffff);
        a1 += bfbits2f(u >> 16);
    }
    float inv = 1.f / fmaxf((float)d, 1.f);
    size_t o = (size_t)node * 16 + c2 * 2;
    outp[o]     += a0 * inv + b2[c2 * 2];
    outp[o + 1] += a1 * inv + b2[c2 * 2 + 1];
}

extern "C" void kernel_launch(void* const* d_in, const int* in_sizes, int n_in,
                              void* d_out, int out_size, void* d_ws, size_t ws_size,
                              hipStream_t stream) {
    const float* x   = (const float*)d_in[0];
    const int*   src = (const int*)d_in[1];
    const int*   dst = (const int*)d_in[2];
    const float* Ws1 = (const float*)d_in[3];
    const float* Wn1 = (const float*)d_in[4];
    const float* b1  = (const float*)d_in[5];
    const float* Ws2 = (const float*)d_in[6];
    const float* Wn2 = (const float*)d_in[7];
    const float* b2  = (const float*)d_in[8];
    float* outp = (float*)d_out;

    const int N = in_sizes[0] / FEATS;   // 50000
    const int E = in_sizes[1];           // 800000
    const int B = (N + 255) / 256;       // buckets (196) — must be <= 256

    // workspace: bucket_cnt[256] | epart[B*CAP] | csr[B*CAP] | row_start[N] |
    // deg16[N] u16 | selfo bf16[N*64] | t1 fp8[N*64] | h1 bf16[N*64] | t2 bf16[N*16]
    char* p = (char*)d_ws;
    auto align16 = [](char* q) { return (char*)(((size_t)q + 15) & ~(size_t)15); };
    int* bucket_cnt    = (int*)p;                  p = (char*)(bucket_cnt + 256);
    int* epart         = (int*)p;                  p = (char*)(epart + (size_t)B * CAP);
    int* csr           = (int*)p;                  p = (char*)(csr + (size_t)B * CAP);
    int* row_start     = (int*)align16(p);         p = (char*)(row_start + N);
    unsigned short* deg16 = (unsigned short*)align16(p); p = (char*)(deg16 + N);
    bf16_t* selfo      = (bf16_t*)align16(p);      p = (char*)(selfo + (size_t)N * 64);
    unsigned char* t1  = (unsigned char*)align16(p); p = (char*)(t1 + (size_t)N * 64);
    bf16_t* h1         = (bf16_t*)align16(p);      p = (char*)(h1 + (size_t)N * 64);
    bf16_t* t2         = (bf16_t*)align16(p);

    hipMemsetAsync(bucket_cnt, 0, 256 * sizeof(int), stream);

    partition_kernel<<<(E + 256 * EPT - 1) / (256 * EPT), 256, 0, stream>>>(
        src, dst, bucket_cnt, epart, E);
    buildcsr_kernel<<<B, 256, 0, stream>>>(epart, bucket_cnt, row_start, deg16, csr, N);

    gemm1_kernel<<<(N + 127) / 128, 256, 0, stream>>>(x, Ws1, Wn1, selfo, t1, N);
    gather64_kernel<<<((size_t)N * 64 + 255) / 256, 256, 0, stream>>>(
        csr, row_start, deg16, t1, selfo, h1, b1, N);
    gemm2_kernel<<<(N + 127) / 128, 256, 0, stream>>>(h1, Ws2, Wn2, outp, t2, N);
    gather16_kernel<<<((size_t)N * 8 + 255) / 256, 256, 0, stream>>>(
        csr, row_start, deg16, t2, outp, b2, N);
}

// Round 12
// 162.073 us; speedup vs baseline: 3.5250x; 1.0228x over previous
//
#include <hip/hip_runtime.h>
#include <hip/hip_bf16.h>
#include <cstring>

// GraphSAGE 2-layer, CSR-gather formulation (no float atomics).
//   h1 = relu(x@Ws1 + mean_agg(x)@Wn1 + b1)
//   out = h1@Ws2 + mean_agg(h1)@Wn2 + b2
// mean_agg(h)@W == mean_agg(h@W): project first, then aggregate projected rows.
// CSR via fixed-capacity bucket sort. partition and gemm1 have NO data
// dependency -> fused into ONE dispatch (role by blockIdx): partition's 196
// blocks under-fill the 256 CUs and are memory/LDS-atomic-bound; gemm1's 391
// VALU-bound blocks fill the rest and co-schedule (MFMA/VALU/mem pipes are
// independent). Single 66KB LDS allocation shared by role.
// t1 fp8 e4m3 (3.2 MB, L2-resident gather table); selfo/h1/t2 bf16; fp32 acc.
// R9 lesson: LDS float atomics for aggregation = 356 us disaster.

#define FEATS 64
#define CLS   16
#define EPT   16      // edges/thread in partition role (4096 edges/block)
#define CAP   5120    // bucket capacity; mean 4081 edges/bucket, 16 sigma margin

typedef unsigned short bf16_t;
typedef float floatx2 __attribute__((ext_vector_type(2)));

__device__ __forceinline__ float bfbits2f(unsigned lo16) {
    unsigned v = lo16 << 16;
    float f;
    __builtin_memcpy(&f, &v, 4);
    return f;
}
__device__ __forceinline__ bf16_t f2bf(float f) {
    unsigned u;
    __builtin_memcpy(&u, &f, 4);
    u = (u + 0x7FFFu + ((u >> 16) & 1u)) >> 16;   // round-to-nearest-even
    return (bf16_t)u;
}
__device__ __forceinline__ unsigned pack2(float a, float b) {
    return (unsigned)f2bf(a) | ((unsigned)f2bf(b) << 16);
}
// pack 4 f32 -> 4 fp8 e4m3 in one dword (HW cvt, RNE)
__device__ __forceinline__ unsigned pack4_fp8(float a, float b, float c, float d) {
    int q = __builtin_amdgcn_cvt_pk_fp8_f32(a, b, 0, false);
    q = __builtin_amdgcn_cvt_pk_fp8_f32(c, d, q, true);
    return (unsigned)q;
}

// ---------------- fused: partition (blocks [0,nbp)) + GEMM1 (blocks [nbp, nbp+nbg)) ----------------
// partition: scatter packed (src<<8)|(dst&255) into fixed-cap buckets.
// gemm1: [N,64] x [64,128] -> selfo [N,64] bf16, t1 [N,64] fp8.
__global__ __launch_bounds__(256) void fused_pg_kernel(
    const int* __restrict__ src, const int* __restrict__ dst,
    int* __restrict__ bucket_cnt, int* __restrict__ epart, int E,
    const float* __restrict__ x, const float* __restrict__ Ws,
    const float* __restrict__ Wn, bf16_t* __restrict__ selfo,
    unsigned char* __restrict__ t1, int N, int nbp)
{
    __shared__ float smem[16512];   // 66 KB: gemm1 Wc[8192]+xs[8320]; partition hist/base
    int t = threadIdx.x;

    if ((int)blockIdx.x < nbp) {
        // ---- partition role ----
        int* hist = (int*)smem;
        int* base = hist + 256;
        int e0 = blockIdx.x * (256 * EPT);
        hist[t] = 0;
        __syncthreads();
        int pk[EPT];
        int bk[EPT];
#pragma unroll
        for (int j = 0; j < EPT; ++j) {
            int e = e0 + j * 256 + t;
            if (e < E) {
                int d = dst[e];
                pk[j] = (src[e] << 8) | (d & 255);
                bk[j] = d >> 8;
                atomicAdd(&hist[bk[j]], 1);
            } else bk[j] = -1;
        }
        __syncthreads();
        int c = hist[t];
        if (c) base[t] = atomicAdd(&bucket_cnt[t], c);
        hist[t] = 0;
        __syncthreads();
#pragma unroll
        for (int j = 0; j < EPT; ++j) {
            if (bk[j] >= 0) {
                int r = atomicAdd(&hist[bk[j]], 1);
                epart[bk[j] * CAP + base[bk[j]] + r] = pk[j];
            }
        }
        return;
    }

    // ---- gemm1 role ----
    float* Wc = smem;           // 64*128
    float* xs = smem + 8192;    // 128*65
    int node0 = ((int)blockIdx.x - nbp) * 128;

    for (int idx = t; idx < 64 * 128; idx += 256) {
        int k = idx >> 7, c = idx & 127;
        Wc[idx] = (c < 64) ? Ws[k * 64 + c] : Wn[k * 64 + (c - 64)];
    }
    for (int idx = t; idx < 128 * 16; idx += 256) {
        int row = idx >> 4, c4 = idx & 15;
        int node = node0 + row;
        float4 v = (node < N) ? ((const float4*)(x + (size_t)node * 64))[c4]
                              : make_float4(0.f, 0.f, 0.f, 0.f);
        float* p = &xs[row * 65 + c4 * 4];
        p[0] = v.x; p[1] = v.y; p[2] = v.z; p[3] = v.w;
    }
    __syncthreads();

    int m = t & 31;
    int g = t >> 5;            // 8 col-groups of 16
    float acc[4][16];
#pragma unroll
    for (int j = 0; j < 4; ++j)
#pragma unroll
        for (int c = 0; c < 16; ++c) acc[j][c] = 0.f;

    for (int k = 0; k < 64; ++k) {
        float w[16];
        const float* wp = &Wc[k * 128 + g * 16];
#pragma unroll
        for (int c = 0; c < 16; ++c) w[c] = wp[c];
        float a0 = xs[m * 65 + k];
        float a1 = xs[(m + 32) * 65 + k];
        float a2 = xs[(m + 64) * 65 + k];
        float a3 = xs[(m + 96) * 65 + k];
#pragma unroll
        for (int c = 0; c < 16; ++c) {
            acc[0][c] += a0 * w[c];
            acc[1][c] += a1 * w[c];
            acc[2][c] += a2 * w[c];
            acc[3][c] += a3 * w[c];
        }
    }
#pragma unroll
    for (int j = 0; j < 4; ++j) {
        int node = node0 + m + 32 * j;
        if (node < N) {
            if (g < 4) {
                bf16_t* dstp = selfo + (size_t)node * 64 + g * 16;
                uint4 p0, p1;
                p0.x = pack2(acc[j][0],  acc[j][1]);  p0.y = pack2(acc[j][2],  acc[j][3]);
                p0.z = pack2(acc[j][4],  acc[j][5]);  p0.w = pack2(acc[j][6],  acc[j][7]);
                p1.x = pack2(acc[j][8],  acc[j][9]);  p1.y = pack2(acc[j][10], acc[j][11]);
                p1.z = pack2(acc[j][12], acc[j][13]); p1.w = pack2(acc[j][14], acc[j][15]);
                *(uint4*)(dstp) = p0;
                *(uint4*)(dstp + 8) = p1;
            } else {
                unsigned char* dstp = t1 + (size_t)node * 64 + (g - 4) * 16;
                uint4 q;
                q.x = pack4_fp8(acc[j][0],  acc[j][1],  acc[j][2],  acc[j][3]);
                q.y = pack4_fp8(acc[j][4],  acc[j][5],  acc[j][6],  acc[j][7]);
                q.z = pack4_fp8(acc[j][8],  acc[j][9],  acc[j][10], acc[j][11]);
                q.w = pack4_fp8(acc[j][12], acc[j][13], acc[j][14], acc[j][15]);
                *(uint4*)(dstp) = q;
            }
        }
    }
}

// ---------------- per-bucket CSR build, all bookkeeping in LDS ----------------
__global__ __launch_bounds__(256) void buildcsr_kernel(const int* __restrict__ epart,
                                                       const int* __restrict__ bucket_cnt,
                                                       int* __restrict__ row_start,
                                                       unsigned short* __restrict__ deg16,
                                                       int* __restrict__ csr, int N) {
    __shared__ int cnt[256];
    __shared__ int pref[256];
    __shared__ int s[256];
    int t = threadIdx.x;
    int b = blockIdx.x;
    int ebeg = b * CAP;
    int ecnt = bucket_cnt[b];
    cnt[t] = 0;
    __syncthreads();
    for (int e = t; e < ecnt; e += 256)
        atomicAdd(&cnt[epart[ebeg + e] & 255], 1);
    __syncthreads();
    int v = cnt[t];
    s[t] = v;
    __syncthreads();
    for (int off = 1; off < 256; off <<= 1) {
        int u = (t >= off) ? s[t - off] : 0;
        __syncthreads();
        s[t] += u;
        __syncthreads();
    }
    pref[t] = s[t] - v;
    int node = b * 256 + t;
    if (node < N) {
        row_start[node] = ebeg + pref[t];
        deg16[node] = (unsigned short)v;
    }
    cnt[t] = 0;
    __syncthreads();
    for (int e = t; e < ecnt; e += 256) {
        int pk = epart[ebeg + e];
        int ln = pk & 255;
        int r = atomicAdd(&cnt[ln], 1);
        csr[ebeg + pref[ln] + r] = pk >> 8;
    }
}

// ---------------- gather64: h1 = relu(selfo + (sum t1[src])/deg + b1) ----------------
__global__ __launch_bounds__(256) void gather64_kernel(
    const int* __restrict__ csr, const int* __restrict__ row_start,
    const unsigned short* __restrict__ deg16,
    const unsigned char* __restrict__ t1, const bf16_t* __restrict__ selfo,
    bf16_t* __restrict__ h1, const float* __restrict__ b1, int N)
{
    int wid = (blockIdx.x * 256 + threadIdx.x) >> 6;
    int lane = threadIdx.x & 63;
    int eslot = lane >> 4;       // 0..3
    int cg = lane & 15;          // cols [cg*4, cg*4+4)
    if (wid >= N) return;
    int beg = row_start[wid];
    int d = deg16[wid];
    float ax = 0.f, ay = 0.f, az = 0.f, aw = 0.f;
    int i = eslot;
    for (; i + 12 < d; i += 16) {
        int s0 = csr[beg + i];
        int s1 = csr[beg + i + 4];
        int s2 = csr[beg + i + 8];
        int s3 = csr[beg + i + 12];
        unsigned r0 = *(const unsigned*)(t1 + (size_t)s0 * 64 + cg * 4);
        unsigned r1 = *(const unsigned*)(t1 + (size_t)s1 * 64 + cg * 4);
        unsigned r2 = *(const unsigned*)(t1 + (size_t)s2 * 64 + cg * 4);
        unsigned r3 = *(const unsigned*)(t1 + (size_t)s3 * 64 + cg * 4);
        floatx2 p0 = __builtin_amdgcn_cvt_pk_f32_fp8((int)r0, false);
        floatx2 q0 = __builtin_amdgcn_cvt_pk_f32_fp8((int)r0, true);
        floatx2 p1 = __builtin_amdgcn_cvt_pk_f32_fp8((int)r1, false);
        floatx2 q1 = __builtin_amdgcn_cvt_pk_f32_fp8((int)r1, true);
        floatx2 p2 = __builtin_amdgcn_cvt_pk_f32_fp8((int)r2, false);
        floatx2 q2 = __builtin_amdgcn_cvt_pk_f32_fp8((int)r2, true);
        floatx2 p3 = __builtin_amdgcn_cvt_pk_f32_fp8((int)r3, false);
        floatx2 q3 = __builtin_amdgcn_cvt_pk_f32_fp8((int)r3, true);
        ax += p0.x + p1.x + p2.x + p3.x;
        ay += p0.y + p1.y + p2.y + p3.y;
        az += q0.x + q1.x + q2.x + q3.x;
        aw += q0.y + q1.y + q2.y + q3.y;
    }
    for (; i < d; i += 4) {
        int s0 = csr[beg + i];
        unsigned r0 = *(const unsigned*)(t1 + (size_t)s0 * 64 + cg * 4);
        floatx2 p0 = __builtin_amdgcn_cvt_pk_f32_fp8((int)r0, false);
        floatx2 q0 = __builtin_amdgcn_cvt_pk_f32_fp8((int)r0, true);
        ax += p0.x; ay += p0.y; az += q0.x; aw += q0.y;
    }
    ax += __shfl_xor(ax, 16); ay += __shfl_xor(ay, 16);
    az += __shfl_xor(az, 16); aw += __shfl_xor(aw, 16);
    ax += __shfl_xor(ax, 32); ay += __shfl_xor(ay, 32);
    az += __shfl_xor(az, 32); aw += __shfl_xor(aw, 32);
    if (eslot == 0) {
        float inv = 1.f / fmaxf((float)d, 1.f);
        size_t o = (size_t)wid * 64 + cg * 4;
        uint2 su = *(const uint2*)(selfo + o);
        float4 bb = *(const float4*)(b1 + cg * 4);
        float rx = fmaxf(bfbits2f(su.x & 0xffff) + ax * inv + bb.x, 0.f);
        float ry = fmaxf(bfbits2f(su.x >> 16)    + ay * inv + bb.y, 0.f);
        float rz = fmaxf(bfbits2f(su.y & 0xffff) + az * inv + bb.z, 0.f);
        float rw = fmaxf(bfbits2f(su.y >> 16)    + aw * inv + bb.w, 0.f);
        uint2 pk;
        pk.x = pack2(rx, ry);
        pk.y = pack2(rz, rw);
        *(uint2*)(h1 + o) = pk;
    }
}

// ---------------- GEMM2: h1(bf16) [N,64] x [64,32] -> out(self) [N,16] f32, t2 [N,16] bf16 ----------------
__global__ __launch_bounds__(256) void gemm2_kernel(
    const bf16_t* __restrict__ h1, const float* __restrict__ Ws,
    const float* __restrict__ Wn, float* __restrict__ outp,
    bf16_t* __restrict__ t2, int N)
{
    __shared__ float Wc[64 * 32];    // 8 KB
    __shared__ float xs[128 * 65];   // 33.3 KB
    int t = threadIdx.x;
    int node0 = blockIdx.x * 128;

    for (int idx = t; idx < 64 * 32; idx += 256) {
        int k = idx >> 5, c = idx & 31;
        Wc[idx] = (c < 16) ? Ws[k * 16 + c] : Wn[k * 16 + (c - 16)];
    }
    for (int idx = t; idx < 128 * 8; idx += 256) {
        int row = idx >> 3, c8 = idx & 7;
        int node = node0 + row;
        float* p = &xs[row * 65 + c8 * 8];
        if (node < N) {
            uint4 u = *(const uint4*)(h1 + (size_t)node * 64 + c8 * 8);
            p[0] = bfbits2f(u.x & 0xffff); p[1] = bfbits2f(u.x >> 16);
            p[2] = bfbits2f(u.y & 0xffff); p[3] = bfbits2f(u.y >> 16);
            p[4] = bfbits2f(u.z & 0xffff); p[5] = bfbits2f(u.z >> 16);
            p[6] = bfbits2f(u.w & 0xffff); p[7] = bfbits2f(u.w >> 16);
        } else {
            for (int qq = 0; qq < 8; ++qq) p[qq] = 0.f;
        }
    }
    __syncthreads();

    int m = t & 31;
    int g = t >> 5;            // 8 col-groups of 4
    float acc[4][4];
#pragma unroll
    for (int j = 0; j < 4; ++j)
#pragma unroll
        for (int c = 0; c < 4; ++c) acc[j][c] = 0.f;

    for (int k = 0; k < 64; ++k) {
        float w[4];
        const float* wp = &Wc[k * 32 + g * 4];
#pragma unroll
        for (int c = 0; c < 4; ++c) w[c] = wp[c];
        float a0 = xs[m * 65 + k];
        float a1 = xs[(m + 32) * 65 + k];
        float a2 = xs[(m + 64) * 65 + k];
        float a3 = xs[(m + 96) * 65 + k];
#pragma unroll
        for (int c = 0; c < 4; ++c) {
            acc[0][c] += a0 * w[c];
            acc[1][c] += a1 * w[c];
            acc[2][c] += a2 * w[c];
            acc[3][c] += a3 * w[c];
        }
    }
#pragma unroll
    for (int j = 0; j < 4; ++j) {
        int node = node0 + m + 32 * j;
        if (node < N) {
            if (g < 4) {
                *(float4*)(outp + (size_t)node * 16 + g * 4) =
                    make_float4(acc[j][0], acc[j][1], acc[j][2], acc[j][3]);
            } else {
                uint2 pk;
                pk.x = pack2(acc[j][0], acc[j][1]);
                pk.y = pack2(acc[j][2], acc[j][3]);
                *(uint2*)(t2 + (size_t)node * 16 + (g - 4) * 4) = pk;
            }
        }
    }
}

// ---------------- gather16: out += (sum t2[src])/deg + b2 ----------------
__global__ __launch_bounds__(256) void gather16_kernel(
    const int* __restrict__ csr, const int* __restrict__ row_start,
    const unsigned short* __restrict__ deg16,
    const bf16_t* __restrict__ t2,
    float* __restrict__ outp, const float* __restrict__ b2, int N)
{
    int gt = blockIdx.x * 256 + threadIdx.x;
    int node = gt >> 3;
    int c2 = gt & 7;             // cols [c2*2, c2*2+2)
    if (node >= N) return;
    int beg = row_start[node];
    int d = deg16[node];
    int end = beg + d;
    float a0 = 0.f, a1 = 0.f;
    int i = beg;
    for (; i + 4 <= end; i += 4) {
        int s0 = csr[i], s1 = csr[i + 1], s2 = csr[i + 2], s3 = csr[i + 3];
        unsigned u0 = *(const unsigned*)(t2 + (size_t)s0 * 16 + c2 * 2);
        unsigned u1 = *(const unsigned*)(t2 + (size_t)s1 * 16 + c2 * 2);
        unsigned u2 = *(const unsigned*)(t2 + (size_t)s2 * 16 + c2 * 2);
        unsigned u3 = *(const unsigned*)(t2 + (size_t)s3 * 16 + c2 * 2);
        a0 += bfbits2f(u0 & 0xffff) + bfbits2f(u1 & 0xffff)
            + bfbits2f(u2 & 0xffff) + bfbits2f(u3 & 0xffff);
        a1 += bfbits2f(u0 >> 16) + bfbits2f(u1 >> 16)
            + bfbits2f(u2 >> 16) + bfbits2f(u3 >> 16);
    }
    for (; i < end; ++i) {
        int s = csr[i];
        unsigned u = *(const unsigned*)(t2 + (size_t)s * 16 + c2 * 2);
        a0 += bfbits2f(u & 0xffff);
        a1 += bfbits2f(u >> 16);
    }
    float inv = 1.f / fmaxf((float)d, 1.f);
    size_t o = (size_t)node * 16 + c2 * 2;
    outp[o]     += a0 * inv + b2[c2 * 2];
    outp[o + 1] += a1 * inv + b2[c2 * 2 + 1];
}

extern "C" void kernel_launch(void* const* d_in, const int* in_sizes, int n_in,
                              void* d_out, int out_size, void* d_ws, size_t ws_size,
                              hipStream_t stream) {
    const float* x   = (const float*)d_in[0];
    const int*   src = (const int*)d_in[1];
    const int*   dst = (const int*)d_in[2];
    const float* Ws1 = (const float*)d_in[3];
    const float* Wn1 = (const float*)d_in[4];
    const float* b1  = (const float*)d_in[5];
    const float* Ws2 = (const float*)d_in[6];
    const float* Wn2 = (const float*)d_in[7];
    const float* b2  = (const float*)d_in[8];
    float* outp = (float*)d_out;

    const int N = in_sizes[0] / FEATS;   // 50000
    const int E = in_sizes[1];           // 800000
    const int B = (N + 255) / 256;       // buckets (196) — must be <= 256
    const int NBP = (E + 256 * EPT - 1) / (256 * EPT);   // partition blocks (196)
    const int NBG = (N + 127) / 128;                     // gemm1 blocks (391)

    // workspace: bucket_cnt[256] | epart[B*CAP] | csr[B*CAP] | row_start[N] |
    // deg16[N] u16 | selfo bf16[N*64] | t1 fp8[N*64] | h1 bf16[N*64] | t2 bf16[N*16]
    char* p = (char*)d_ws;
    auto align16 = [](char* q) { return (char*)(((size_t)q + 15) & ~(size_t)15); };
    int* bucket_cnt    = (int*)p;                  p = (char*)(bucket_cnt + 256);
    int* epart         = (int*)p;                  p = (char*)(epart + (size_t)B * CAP);
    int* csr           = (int*)p;                  p = (char*)(csr + (size_t)B * CAP);
    int* row_start     = (int*)align16(p);         p = (char*)(row_start + N);
    unsigned short* deg16 = (unsigned short*)align16(p); p = (char*)(deg16 + N);
    bf16_t* selfo      = (bf16_t*)align16(p);      p = (char*)(selfo + (size_t)N * 64);
    unsigned char* t1  = (unsigned char*)align16(p); p = (char*)(t1 + (size_t)N * 64);
    bf16_t* h1         = (bf16_t*)align16(p);      p = (char*)(h1 + (size_t)N * 64);
    bf16_t* t2         = (bf16_t*)align16(p);

    hipMemsetAsync(bucket_cnt, 0, 256 * sizeof(int), stream);

    fused_pg_kernel<<<NBP + NBG, 256, 0, stream>>>(
        src, dst, bucket_cnt, epart, E, x, Ws1, Wn1, selfo, t1, N, NBP);
    buildcsr_kernel<<<B, 256, 0, stream>>>(epart, bucket_cnt, row_start, deg16, csr, N);

    gather64_kernel<<<((size_t)N * 64 + 255) / 256, 256, 0, stream>>>(
        csr, row_start, deg16, t1, selfo, h1, b1, N);
    gemm2_kernel<<<(N + 127) / 128, 256, 0, stream>>>(h1, Ws2, Wn2, outp, t2, N);
    gather16_kernel<<<((size_t)N * 8 + 255) / 256, 256, 0, stream>>>(
        csr, row_start, deg16, t2, outp, b2, N);
}